// Round 10
// baseline (377.892 us; speedup 1.0000x reference)
//
#include <hip/hip_runtime.h>
#include <hip/hip_bf16.h>
#include <math.h>

// CrossAttention: B=2, N=M=2048, D=1024, H=16, Dh=64
#define BATCH   2
#define NQ      2048
#define NKV     2048
#define DMODEL  1024
#define HEADS   16
#define INNER   1024
#define KVCOLS  2048

typedef short bf16x8 __attribute__((ext_vector_type(8)));
typedef float f32x4  __attribute__((ext_vector_type(4)));

__device__ __forceinline__ short f2bf(float x) {
    __hip_bfloat16 h = __float2bfloat16(x);   // RNE
    return *reinterpret_cast<short*>(&h);
}
__device__ __forceinline__ float bf2f(short h) {
    unsigned int u = ((unsigned int)(unsigned short)h) << 16;
    float f;
    __builtin_memcpy(&f, &u, 4);
    return f;
}
// async 16B global->LDS; per-wave lane-contiguous dest convention (m104)
__device__ __forceinline__ void gl_lds16(const void* g, void* l) {
    __builtin_amdgcn_global_load_lds(
        (const __attribute__((address_space(1))) unsigned int*)g,
        (__attribute__((address_space(3))) unsigned int*)l, 16, 0, 0);
}
// XOR chunk swizzle for stride-64-short LDS rows (chunk = 8 shorts = 16 B)
__device__ __forceinline__ int sw(int row, int chunk) {
    return row * 64 + ((chunk ^ (row & 7)) << 3);
}

// ---------------------------------------------------------------------------
// fused prep: split x, split ctx, transpose(+split) all weights. 12288 blocks.
// ---------------------------------------------------------------------------
__device__ __forceinline__ void split_chunk(const float* __restrict__ in,
                                            short* __restrict__ hi,
                                            short* __restrict__ lo, int id)
{
    const int i = (id * 256 + (int)threadIdx.x) * 4;
    float4 v = *(const float4*)(in + i);
    short4 h, l;
    h.x = f2bf(v.x); l.x = f2bf(v.x - bf2f(h.x));
    h.y = f2bf(v.y); l.y = f2bf(v.y - bf2f(h.y));
    h.z = f2bf(v.z); l.z = f2bf(v.z - bf2f(h.z));
    h.w = f2bf(v.w); l.w = f2bf(v.w - bf2f(h.w));
    *(short4*)(hi + i) = h;
    *(short4*)(lo + i) = l;
}

__device__ __forceinline__ void tile_transpose_split(
    const float* __restrict__ W, short* __restrict__ Wth, short* __restrict__ Wtl,
    int Kd, int Nd, int bx, int by, int split)
{
    __shared__ float t[32][33];
    const int lx = threadIdx.x & 31, ly = threadIdx.x >> 5;
    #pragma unroll
    for (int j = 0; j < 4; ++j)
        t[ly + j * 8][lx] = W[(size_t)(by * 32 + ly + j * 8) * Nd + bx * 32 + lx];
    __syncthreads();
    #pragma unroll
    for (int j = 0; j < 4; ++j) {
        const float v = t[lx][ly + j * 8];
        const short h = f2bf(v);
        const size_t idx = (size_t)(bx * 32 + ly + j * 8) * Kd + by * 32 + lx;
        Wth[idx] = h;
        if (split) Wtl[idx] = f2bf(v - bf2f(h));
    }
}

__global__ __launch_bounds__(256)
void prep_all(const float* __restrict__ x, const float* __restrict__ ctx,
              const float* __restrict__ Wq, const float* __restrict__ Wkv,
              const float* __restrict__ Wout,
              short* __restrict__ xh, short* __restrict__ xl,
              short* __restrict__ ch, short* __restrict__ cl,
              short* __restrict__ WqTh, short* __restrict__ WqTl,
              short* __restrict__ WkvTh, short* __restrict__ WkvTl,
              short* __restrict__ WoutT)
{
    const int id = blockIdx.x;
    if (id < 4096) {
        split_chunk(x, xh, xl, id);
    } else if (id < 8192) {
        split_chunk(ctx, ch, cl, id - 4096);
    } else {
        const int r = id - 8192;
        if (r < 1024)
            tile_transpose_split(Wq, WqTh, WqTl, 1024, 1024, r & 31, r >> 5, 1);
        else if (r < 3072)
            tile_transpose_split(Wkv, WkvTh, WkvTl, 1024, 2048, (r - 1024) & 63, (r - 1024) >> 6, 1);
        else
            tile_transpose_split(Wout, WoutT, nullptr, 1024, 1024, (r - 3072) & 31, (r - 3072) >> 5, 0);
    }
}

// ---------------------------------------------------------------------------
// Fused q/k/v GEMM v3: all operands LDS-staged (A re-fetch bug of v2 fixed),
// flash-v5-style double-buffered staging: global->reg prefetch issued before
// the barrier, ds_write after compute, SINGLE barrier per K-step (32 vs 64).
// No gl_lds -> barrier doesn't drain staging vmcnt (the m97 stall).
// Tile 128x128, BK=32, 256 threads = 4 waves (wave 64x64), LDS 64 KB.
// Grid (8, 32, 3): z=0 q (3-term, *0.125, split out), z=1 k (3-term, split),
// z=2 v (1-term, bf16). 3-term: C = Ah*Bh + Ah*Bl + Al*Bh.
// LDS layout [row][chunk^(row&3)] -> 2-way (free) read conflicts.
// ---------------------------------------------------------------------------
__global__ __launch_bounds__(256)
void qkv_gemm(const short* __restrict__ xh, const short* __restrict__ xl,
              const short* __restrict__ ch, const short* __restrict__ cl,
              const short* __restrict__ WqTh, const short* __restrict__ WqTl,
              const short* __restrict__ WkvTh, const short* __restrict__ WkvTl,
              short* __restrict__ qhp, short* __restrict__ qlp,
              short* __restrict__ khp, short* __restrict__ klp,
              short* __restrict__ vp)
{
    __shared__ short Ash[2][128 * 32];   // 8 KB per buf per plane, 64 KB total
    __shared__ short Asl[2][128 * 32];
    __shared__ short Bsh[2][128 * 32];
    __shared__ short Bsl[2][128 * 32];

    const int tid = threadIdx.x;
    const int z = blockIdx.z;
    const int m0 = blockIdx.y * 128, n0 = blockIdx.x * 128;
    const int w = tid >> 6, ln = tid & 63;
    const int wm = (w & 1) * 64, wn = (w >> 1) * 64;
    const int lr = ln & 15, lq = ln >> 4;
    const int terms = (z == 2) ? 1 : 3;

    const short* Ah  = (z == 0) ? xh : ch;
    const short* Al  = (z == 0) ? xl : cl;
    const short* Bth = (z == 0) ? WqTh : (z == 1 ? WkvTh : WkvTh + (size_t)1024 * 1024);
    const short* Btl = (z == 0) ? WqTl : WkvTl;   // unused for z==2

    // staging map: plane = 128 rows x 4 chunks(16B) = 512 chunks, 2/thread.
    // global chunk fetched for (row,c) is c^(row&3); LDS[row][c] at f*8.
    const int f0r = tid >> 2,         f0c = tid & 3;
    const int f1r = (256 + tid) >> 2, f1c = tid & 3;   // f1 = 256+tid
    const int g0 = f0c ^ (f0r & 3), g1 = f1c ^ (f1r & 3);

    int4 pah[2], pal[2], pbh[2], pbl[2];

    f32x4 acc[4][4];
    #pragma unroll
    for (int mt = 0; mt < 4; ++mt)
        #pragma unroll
        for (int nt = 0; nt < 4; ++nt)
            #pragma unroll
            for (int r = 0; r < 4; ++r) acc[mt][nt][r] = 0.0f;

    // prologue: load + stage k0=0 into buf 0
    {
        const size_t a0 = (size_t)(m0 + f0r) * 1024 + g0 * 8;
        const size_t a1 = (size_t)(m0 + f1r) * 1024 + g1 * 8;
        const size_t b0 = (size_t)(n0 + f0r) * 1024 + g0 * 8;
        const size_t b1 = (size_t)(n0 + f1r) * 1024 + g1 * 8;
        pah[0] = *(const int4*)(Ah + a0);  pah[1] = *(const int4*)(Ah + a1);
        pbh[0] = *(const int4*)(Bth + b0); pbh[1] = *(const int4*)(Bth + b1);
        *(int4*)(&Ash[0][tid * 8])         = pah[0];
        *(int4*)(&Ash[0][(256 + tid) * 8]) = pah[1];
        *(int4*)(&Bsh[0][tid * 8])         = pbh[0];
        *(int4*)(&Bsh[0][(256 + tid) * 8]) = pbh[1];
        if (terms == 3) {
            pal[0] = *(const int4*)(Al + a0);  pal[1] = *(const int4*)(Al + a1);
            pbl[0] = *(const int4*)(Btl + b0); pbl[1] = *(const int4*)(Btl + b1);
            *(int4*)(&Asl[0][tid * 8])         = pal[0];
            *(int4*)(&Asl[0][(256 + tid) * 8]) = pal[1];
            *(int4*)(&Bsl[0][tid * 8])         = pbl[0];
            *(int4*)(&Bsl[0][(256 + tid) * 8]) = pbl[1];
        }
    }

    for (int kt = 0; kt < 32; ++kt) {
        const int cur = kt & 1;
        if (kt < 31) {   // prefetch k-step kt+1 into registers
            const int k0 = (kt + 1) * 32;
            const size_t a0 = (size_t)(m0 + f0r) * 1024 + k0 + g0 * 8;
            const size_t a1 = (size_t)(m0 + f1r) * 1024 + k0 + g1 * 8;
            const size_t b0 = (size_t)(n0 + f0r) * 1024 + k0 + g0 * 8;
            const size_t b1 = (size_t)(n0 + f1r) * 1024 + k0 + g1 * 8;
            pah[0] = *(const int4*)(Ah + a0);  pah[1] = *(const int4*)(Ah + a1);
            pbh[0] = *(const int4*)(Bth + b0); pbh[1] = *(const int4*)(Bth + b1);
            if (terms == 3) {
                pal[0] = *(const int4*)(Al + a0);  pal[1] = *(const int4*)(Al + a1);
                pbl[0] = *(const int4*)(Btl + b0); pbl[1] = *(const int4*)(Btl + b1);
            }
        }
        __syncthreads();   // buf[cur] staged; prev iter's reads of buf[cur^1] done

        bf16x8 ah[4], bh[4];
        #pragma unroll
        for (int t = 0; t < 4; ++t) {
            const int ar = wm + t * 16 + lr;
            const int br = wn + t * 16 + lr;
            ah[t] = *(const bf16x8*)(&Ash[cur][ar * 32 + ((lq ^ (ar & 3)) << 3)]);
            bh[t] = *(const bf16x8*)(&Bsh[cur][br * 32 + ((lq ^ (br & 3)) << 3)]);
        }
        #pragma unroll
        for (int mt = 0; mt < 4; ++mt)
            #pragma unroll
            for (int nt = 0; nt < 4; ++nt)
                acc[mt][nt] = __builtin_amdgcn_mfma_f32_16x16x32_bf16(
                    ah[mt], bh[nt], acc[mt][nt], 0, 0, 0);
        if (terms == 3) {
            bf16x8 al[4], bl[4];
            #pragma unroll
            for (int t = 0; t < 4; ++t) {
                const int ar = wm + t * 16 + lr;
                const int br = wn + t * 16 + lr;
                al[t] = *(const bf16x8*)(&Asl[cur][ar * 32 + ((lq ^ (ar & 3)) << 3)]);
                bl[t] = *(const bf16x8*)(&Bsl[cur][br * 32 + ((lq ^ (br & 3)) << 3)]);
            }
            #pragma unroll
            for (int mt = 0; mt < 4; ++mt)
                #pragma unroll
                for (int nt = 0; nt < 4; ++nt) {
                    acc[mt][nt] = __builtin_amdgcn_mfma_f32_16x16x32_bf16(
                        ah[mt], bl[nt], acc[mt][nt], 0, 0, 0);
                    acc[mt][nt] = __builtin_amdgcn_mfma_f32_16x16x32_bf16(
                        al[mt], bh[nt], acc[mt][nt], 0, 0, 0);
                }
        }

        if (kt < 31) {   // stage prefetched regs into buf[cur^1]
            const int nb = cur ^ 1;
            *(int4*)(&Ash[nb][tid * 8])         = pah[0];
            *(int4*)(&Ash[nb][(256 + tid) * 8]) = pah[1];
            *(int4*)(&Bsh[nb][tid * 8])         = pbh[0];
            *(int4*)(&Bsh[nb][(256 + tid) * 8]) = pbh[1];
            if (terms == 3) {
                *(int4*)(&Asl[nb][tid * 8])         = pal[0];
                *(int4*)(&Asl[nb][(256 + tid) * 8]) = pal[1];
                *(int4*)(&Bsl[nb][tid * 8])         = pbl[0];
                *(int4*)(&Bsl[nb][(256 + tid) * 8]) = pbl[1];
            }
        }
    }

    // C/D layout: col = lane&15, row = (lane>>4)*4 + reg
    const float scale = (z == 0) ? 0.125f : 1.0f;
    short* Chi = (z == 0) ? qhp : (z == 1 ? khp : vp);
    short* Clo = (z == 0) ? qlp : klp;
    #pragma unroll
    for (int mt = 0; mt < 4; ++mt)
        #pragma unroll
        for (int nt = 0; nt < 4; ++nt)
            #pragma unroll
            for (int r = 0; r < 4; ++r) {
                const int row = m0 + wm + mt * 16 + lq * 4 + r;
                const int col = n0 + wn + nt * 16 + lr;
                const float v = acc[mt][nt][r] * scale;
                const short hh = f2bf(v);
                Chi[(size_t)row * 1024 + col] = hh;
                if (z != 2)
                    Clo[(size_t)row * 1024 + col] = f2bf(v - bf2f(hh));
            }
}

// ---------------------------------------------------------------------------
// Out-proj GEMM (round-8 version restored): tile 64x64, gl_lds staging,
// 1024 blocks -> 4/CU. fp32 + bias out.
// ---------------------------------------------------------------------------
__global__ __launch_bounds__(256)
void gemm_out(const short* __restrict__ A, const short* __restrict__ Bt,
              float* __restrict__ C, int Md, int Nd, int Kd,
              const float* __restrict__ bias)
{
    __shared__ short As[64 * 64];     // 8 KB
    __shared__ short Bs[64 * 64];     // 8 KB
    const int tid = threadIdx.x;
    const int m0 = blockIdx.y * 64, n0 = blockIdx.x * 64;
    const int w = tid >> 6, ln = tid & 63;
    const int wm = (w & 1) * 32, wn = (w >> 1) * 32;
    const int lr = ln & 15, lq = ln >> 4;

    f32x4 acc[2][2];
    #pragma unroll
    for (int mt = 0; mt < 2; ++mt)
        #pragma unroll
        for (int nt = 0; nt < 2; ++nt)
            #pragma unroll
            for (int r = 0; r < 4; ++r) acc[mt][nt][r] = 0.0f;

    for (int k0 = 0; k0 < Kd; k0 += 64) {
        __syncthreads();
        #pragma unroll
        for (int it = 0; it < 2; ++it) {          // 512 chunks per matrix
            const int f = it * 256 + tid;
            const int row = f >> 3, c8 = f & 7;
            gl_lds16(A  + (size_t)(m0 + row) * Kd + k0 + c8 * 8, As + f * 8);
            gl_lds16(Bt + (size_t)(n0 + row) * Kd + k0 + c8 * 8, Bs + f * 8);
        }
        __syncthreads();
        #pragma unroll
        for (int ks = 0; ks < 2; ++ks) {
            bf16x8 af[2], bfr[2];
            #pragma unroll
            for (int t = 0; t < 2; ++t) {
                af[t]  = *(const bf16x8*)(As + (wm + t * 16 + lr) * 64 + ks * 32 + lq * 8);
                bfr[t] = *(const bf16x8*)(Bs + (wn + t * 16 + lr) * 64 + ks * 32 + lq * 8);
            }
            #pragma unroll
            for (int mt = 0; mt < 2; ++mt)
                #pragma unroll
                for (int nt = 0; nt < 2; ++nt)
                    acc[mt][nt] = __builtin_amdgcn_mfma_f32_16x16x32_bf16(
                        af[mt], bfr[nt], acc[mt][nt], 0, 0, 0);
        }
    }
    #pragma unroll
    for (int mt = 0; mt < 2; ++mt)
        #pragma unroll
        for (int nt = 0; nt < 2; ++nt)
            #pragma unroll
            for (int r = 0; r < 4; ++r) {
                const int row = m0 + wm + mt * 16 + lq * 4 + r;
                const int col = n0 + wn + nt * 16 + lr;
                C[(size_t)row * Nd + col] = acc[mt][nt][r] + bias[col];
            }
}

// ---------------------------------------------------------------------------
// MFMA flash attention v6 (unchanged from round 9, absmax-verified):
// single barrier/K-tile, K/V dbuf + register prefetch, key-permuted P/V
// (b64 Ps writes), XOR-swizzled LDS (0 conflicts), fixed-max softmax,
// masked rows on the reference's fp32 "s-1e6" grid rint(s*16)/16.
// 128 q-rows, 512 threads = 8 waves.
// ---------------------------------------------------------------------------
__global__ __launch_bounds__(512, 4)
void flash_v6(const short* __restrict__ qh, const short* __restrict__ ql,
              const short* __restrict__ kh, const short* __restrict__ kl,
              const short* __restrict__ vp, const int* __restrict__ mask,
              short* __restrict__ aob)
{
    const int qt = blockIdx.x, h = blockIdx.y, b = blockIdx.z;
    const int tid = threadIdx.x;
    const int w = tid >> 6, ln = tid & 63;
    const int lr = ln & 15, lq = ln >> 4;

    __shared__ short Kh[2 * 4096];   // 16 KB  [buf][key][d] swizzled
    __shared__ short Kl[2 * 4096];   // 16 KB
    __shared__ short Vt[2 * 4096];   // 16 KB  [buf][d][key'] swizzled
    __shared__ short Ps[128 * 64];   // 16 KB  [row][key'] swizzled (wave-local)

    const size_t qrow0 = (size_t)(b * NQ + qt * 128);

    bf16x8 aqh[2], aql[2];
    #pragma unroll
    for (int ks = 0; ks < 2; ++ks) {
        const size_t qoff = (qrow0 + w * 16 + lr) * INNER + h * 64 + ks * 32 + lq * 8;
        aqh[ks] = *(const bf16x8*)(qh + qoff);
        aql[ks] = *(const bf16x8*)(ql + qoff);
    }
    float keep[4];
    #pragma unroll
    for (int r = 0; r < 4; ++r)
        keep[r] = (float)mask[b * NQ + qt * 128 + w * 16 + lq * 4 + r];

    const int srow = tid >> 3, sc8 = tid & 7;            // K: 64 rows x 8 chunks
    const int kdst = sw(srow, sc8);
    const int idx = tid & 31, dg4 = (tid >> 5) * 4;      // V: key-pairs (j, j+16)
    const int vj  = (idx & 15) + ((idx >> 4) << 5);
    const int kp32 = (idx & 15) * 2 + (idx >> 4);
    int4 rkh, rkl; int2 rva, rvb;

    {   // prologue: load + stage kt=0 into buf 0
        const size_t koff = (size_t)(b * NKV + srow) * INNER + h * 64 + sc8 * 8;
        rkh = *(const int4*)(kh + koff);
        rkl = *(const int4*)(kl + koff);
        const short* v0 = vp + (size_t)(b * NKV + vj) * INNER + h * 64 + dg4;
        rva = *(const int2*)(v0);
        rvb = *(const int2*)(v0 + 16 * INNER);
        *(int4*)(Kh + kdst) = rkh;
        *(int4*)(Kl + kdst) = rkl;
        const short* as = (const short*)&rva;
        const short* bs = (const short*)&rvb;
        int* vt32 = (int*)Vt;
        #pragma unroll
        for (int j = 0; j < 4; ++j)
            vt32[(dg4 + j) * 32 + (((kp32 >> 2) ^ ((dg4 + j) & 7)) << 2) + (kp32 & 3)] =
                (int)((unsigned short)as[j] | ((unsigned int)(unsigned short)bs[j] << 16));
    }

    float psum[4];
    #pragma unroll
    for (int r = 0; r < 4; ++r) psum[r] = 0.0f;
    f32x4 oacc[4];
    #pragma unroll
    for (int dg = 0; dg < 4; ++dg)
        #pragma unroll
        for (int r = 0; r < 4; ++r) oacc[dg][r] = 0.0f;

    for (int kt = 0; kt < NKV / 64; ++kt) {
        const int cur = kt & 1;
        if (kt < NKV / 64 - 1) {
            const size_t krow0 = (size_t)(b * NKV + (kt + 1) * 64);
            const size_t koff = (krow0 + srow) * INNER + h * 64 + sc8 * 8;
            rkh = *(const int4*)(kh + koff);
            rkl = *(const int4*)(kl + koff);
            const short* v0 = vp + (krow0 + vj) * INNER + h * 64 + dg4;
            rva = *(const int2*)(v0);
            rvb = *(const int2*)(v0 + 16 * INNER);
        }
        __syncthreads();

        const short* KhC = Kh + cur * 4096;
        const short* KlC = Kl + cur * 4096;
        const short* VtC = Vt + cur * 4096;

        f32x4 sacc[4];
        #pragma unroll
        for (int g = 0; g < 4; ++g)
            #pragma unroll
            for (int r = 0; r < 4; ++r) sacc[g][r] = 0.0f;
        #pragma unroll
        for (int ks = 0; ks < 2; ++ks) {
            #pragma unroll
            for (int g = 0; g < 4; ++g) {
                const bf16x8 bkh = *(const bf16x8*)(KhC + sw(g * 16 + lr, ks * 4 + lq));
                const bf16x8 bkl = *(const bf16x8*)(KlC + sw(g * 16 + lr, ks * 4 + lq));
                sacc[g] = __builtin_amdgcn_mfma_f32_16x16x32_bf16(aqh[ks], bkh, sacc[g], 0, 0, 0);
                sacc[g] = __builtin_amdgcn_mfma_f32_16x16x32_bf16(aqh[ks], bkl, sacc[g], 0, 0, 0);
                sacc[g] = __builtin_amdgcn_mfma_f32_16x16x32_bf16(aql[ks], bkh, sacc[g], 0, 0, 0);
            }
        }

        // softmax (fixed max=0) + Ps write: keys' lr*4+g contiguous -> b64
        #pragma unroll
        for (int r = 0; r < 4; ++r) {
            const int prow = w * 16 + lq * 4 + r;
            float pv[4];
            #pragma unroll
            for (int g = 0; g < 4; ++g) {
                float s = sacc[g][r];
                if (keep[r] == 0.0f) s = rintf(s * 16.0f) * 0.0625f;
                pv[g] = __expf(s);
                psum[r] += pv[g];
            }
            short4 pw;
            pw.x = f2bf(pv[0]); pw.y = f2bf(pv[1]);
            pw.z = f2bf(pv[2]); pw.w = f2bf(pv[3]);
            *(short4*)(Ps + sw(prow, lr >> 1) + (lr & 1) * 4) = pw;
        }
        // no barrier: Ps rows are wave-local

        #pragma unroll
        for (int ks = 0; ks < 2; ++ks) {
            const bf16x8 ap = *(const bf16x8*)(Ps + sw(w * 16 + lr, ks * 4 + lq));
            #pragma unroll
            for (int dg = 0; dg < 4; ++dg) {
                const bf16x8 bv = *(const bf16x8*)(VtC + sw(dg * 16 + lr, ks * 4 + lq));
                oacc[dg] = __builtin_amdgcn_mfma_f32_16x16x32_bf16(ap, bv, oacc[dg], 0, 0, 0);
            }
        }

        if (kt < NKV / 64 - 1) {
            short* KhN = Kh + (cur ^ 1) * 4096;
            short* KlN = Kl + (cur ^ 1) * 4096;
            *(int4*)(KhN + kdst) = rkh;
            *(int4*)(KlN + kdst) = rkl;
            const short* as = (const short*)&rva;
            const short* bs = (const short*)&rvb;
            int* vt32 = (int*)(Vt + (cur ^ 1) * 4096);
            #pragma unroll
            for (int j = 0; j < 4; ++j)
                vt32[(dg4 + j) * 32 + (((kp32 >> 2) ^ ((dg4 + j) & 7)) << 2) + (kp32 & 3)] =
                    (int)((unsigned short)as[j] | ((unsigned int)(unsigned short)bs[j] << 16));
        }
    }

    #pragma unroll
    for (int off = 1; off < 16; off <<= 1)
        #pragma unroll
        for (int r = 0; r < 4; ++r)
            psum[r] += __shfl_xor(psum[r], off, 64);

    #pragma unroll
    for (int dg = 0; dg < 4; ++dg)
        #pragma unroll
        for (int r = 0; r < 4; ++r) {
            const int row = w * 16 + lq * 4 + r;
            aob[(qrow0 + row) * INNER + h * 64 + dg * 16 + lr] =
                f2bf(oacc[dg][r] / psum[r]);
        }
}

// ---------------------------------------------------------------------------
extern "C" void kernel_launch(void* const* d_in, const int* in_sizes, int n_in,
                              void* d_out, int out_size, void* d_ws, size_t ws_size,
                              hipStream_t stream)
{
    const float* x    = (const float*)d_in[0];
    const float* ctx  = (const float*)d_in[1];
    const int*   mask = (const int*)d_in[2];
    const float* Wq   = (const float*)d_in[3];
    const float* Wkv  = (const float*)d_in[4];
    const float* Wout = (const float*)d_in[5];
    const float* bout = (const float*)d_in[6];
    float* out = (float*)d_out;

    // Workspace: 43M shorts = 86 MB (proven). aob aliases xh (dead after qkv).
    short* base  = (short*)d_ws;
    short* xh    = base;                             // 4M ; aob after qkv
    short* xl    = base + (size_t)4 * 1024 * 1024;   // 4M
    short* aob   = xh;
    short* WqTh  = base + (size_t) 8 * 1024 * 1024;  // 1M
    short* WqTl  = base + (size_t) 9 * 1024 * 1024;  // 1M
    short* qhp   = base + (size_t)10 * 1024 * 1024;  // 4M
    short* qlp   = base + (size_t)14 * 1024 * 1024;  // 4M
    short* WkvTh = base + (size_t)18 * 1024 * 1024;  // 2M
    short* WkvTl = base + (size_t)20 * 1024 * 1024;  // 2M
    short* khp   = base + (size_t)22 * 1024 * 1024;  // 4M
    short* klp   = base + (size_t)26 * 1024 * 1024;  // 4M
    short* WoutT = base + (size_t)30 * 1024 * 1024;  // 1M
    short* ch    = base + (size_t)31 * 1024 * 1024;  // 4M
    short* cl    = base + (size_t)35 * 1024 * 1024;  // 4M
    short* vp    = base + (size_t)39 * 1024 * 1024;  // 4M

    const dim3 blk(256);
    // 1) fused prep: split x, split ctx, transpose(+split) weights
    prep_all<<<12288, blk, 0, stream>>>(x, ctx, Wq, Wkv, Wout,
                                        xh, xl, ch, cl,
                                        WqTh, WqTl, WkvTh, WkvTl, WoutT);
    // 2) fused q/k/v GEMM (LDS dbuf, register prefetch, 1 barrier/K-step)
    qkv_gemm<<<dim3(8, 32, 3), blk, 0, stream>>>(
        xh, xl, ch, cl, WqTh, WqTl, WkvTh, WkvTl,
        qhp, qlp, khp, klp, vp);
    // 3) attention (aob overwrites xh region, dead after qkv)
    flash_v6<<<dim3(NQ / 128, HEADS, BATCH), dim3(512), 0, stream>>>(
        qhp, qlp, khp, klp, vp, mask, aob);
    // 4) out = ao @ Wout + bout -> fp32
    gemm_out<<<dim3(1024 / 64, 4096 / 64), blk, 0, stream>>>(
        aob, WoutT, out, 4096, 1024, 1024, bout);
}

// Round 11
// 299.135 us; speedup vs baseline: 1.2633x; 1.2633x over previous
//
#include <hip/hip_runtime.h>
#include <hip/hip_bf16.h>
#include <math.h>

// CrossAttention: B=2, N=M=2048, D=1024, H=16, Dh=64
#define BATCH   2
#define NQ      2048
#define NKV     2048
#define DMODEL  1024
#define HEADS   16
#define INNER   1024
#define KVCOLS  2048

typedef short bf16x8 __attribute__((ext_vector_type(8)));
typedef float f32x4  __attribute__((ext_vector_type(4)));

__device__ __forceinline__ short f2bf(float x) {
    __hip_bfloat16 h = __float2bfloat16(x);   // RNE
    return *reinterpret_cast<short*>(&h);
}
__device__ __forceinline__ float bf2f(short h) {
    unsigned int u = ((unsigned int)(unsigned short)h) << 16;
    float f;
    __builtin_memcpy(&f, &u, 4);
    return f;
}
// async 16B global->LDS; per-wave lane-contiguous dest convention (m104)
__device__ __forceinline__ void gl_lds16(const void* g, void* l) {
    __builtin_amdgcn_global_load_lds(
        (const __attribute__((address_space(1))) unsigned int*)g,
        (__attribute__((address_space(3))) unsigned int*)l, 16, 0, 0);
}
// XOR chunk swizzle for stride-64-short LDS rows (chunk = 8 shorts = 16 B)
__device__ __forceinline__ int sw(int row, int chunk) {
    return row * 64 + ((chunk ^ (row & 7)) << 3);
}

// ---------------------------------------------------------------------------
// fused prep: split x, split ctx, transpose(+split) all weights. 12288 blocks.
// ---------------------------------------------------------------------------
__device__ __forceinline__ void split_chunk(const float* __restrict__ in,
                                            short* __restrict__ hi,
                                            short* __restrict__ lo, int id)
{
    const int i = (id * 256 + (int)threadIdx.x) * 4;
    float4 v = *(const float4*)(in + i);
    short4 h, l;
    h.x = f2bf(v.x); l.x = f2bf(v.x - bf2f(h.x));
    h.y = f2bf(v.y); l.y = f2bf(v.y - bf2f(h.y));
    h.z = f2bf(v.z); l.z = f2bf(v.z - bf2f(h.z));
    h.w = f2bf(v.w); l.w = f2bf(v.w - bf2f(h.w));
    *(short4*)(hi + i) = h;
    *(short4*)(lo + i) = l;
}

__device__ __forceinline__ void tile_transpose_split(
    const float* __restrict__ W, short* __restrict__ Wth, short* __restrict__ Wtl,
    int Kd, int Nd, int bx, int by, int split)
{
    __shared__ float t[32][33];
    const int lx = threadIdx.x & 31, ly = threadIdx.x >> 5;
    #pragma unroll
    for (int j = 0; j < 4; ++j)
        t[ly + j * 8][lx] = W[(size_t)(by * 32 + ly + j * 8) * Nd + bx * 32 + lx];
    __syncthreads();
    #pragma unroll
    for (int j = 0; j < 4; ++j) {
        const float v = t[lx][ly + j * 8];
        const short h = f2bf(v);
        const size_t idx = (size_t)(bx * 32 + ly + j * 8) * Kd + by * 32 + lx;
        Wth[idx] = h;
        if (split) Wtl[idx] = f2bf(v - bf2f(h));
    }
}

__global__ __launch_bounds__(256)
void prep_all(const float* __restrict__ x, const float* __restrict__ ctx,
              const float* __restrict__ Wq, const float* __restrict__ Wkv,
              const float* __restrict__ Wout,
              short* __restrict__ xh, short* __restrict__ xl,
              short* __restrict__ ch, short* __restrict__ cl,
              short* __restrict__ WqTh, short* __restrict__ WqTl,
              short* __restrict__ WkvTh, short* __restrict__ WkvTl,
              short* __restrict__ WoutT)
{
    const int id = blockIdx.x;
    if (id < 4096) {
        split_chunk(x, xh, xl, id);
    } else if (id < 8192) {
        split_chunk(ctx, ch, cl, id - 4096);
    } else {
        const int r = id - 8192;
        if (r < 1024)
            tile_transpose_split(Wq, WqTh, WqTl, 1024, 1024, r & 31, r >> 5, 1);
        else if (r < 3072)
            tile_transpose_split(Wkv, WkvTh, WkvTl, 1024, 2048, (r - 1024) & 63, (r - 1024) >> 6, 1);
        else
            tile_transpose_split(Wout, WoutT, nullptr, 1024, 1024, (r - 3072) & 31, (r - 3072) >> 5, 0);
    }
}

// ---------------------------------------------------------------------------
// Fused q/k/v GEMM (round-8 version restored verbatim — fastest measured).
// Tile 128x128, BK=32, 256 threads = 4 waves (wave 64x64), LDS 32 KB, gl_lds
// staging with source-chunk XOR permute (c ^ ((row>>1)&3)) -> free LDS reads.
// Grid (8, 32, 3): z=0 q (3-term, *0.125, split out), z=1 k (3-term, split),
// z=2 v (1-term, bf16). 3-term: C = Ah*Bh + Ah*Bl + Al*Bh.
// ---------------------------------------------------------------------------
__global__ __launch_bounds__(256)
void qkv_gemm(const short* __restrict__ xh, const short* __restrict__ xl,
              const short* __restrict__ ch, const short* __restrict__ cl,
              const short* __restrict__ WqTh, const short* __restrict__ WqTl,
              const short* __restrict__ WkvTh, const short* __restrict__ WkvTl,
              short* __restrict__ qhp, short* __restrict__ qlp,
              short* __restrict__ khp, short* __restrict__ klp,
              short* __restrict__ vp)
{
    __shared__ short Ash[128 * 32];   // 8 KB each
    __shared__ short Asl[128 * 32];
    __shared__ short Bsh[128 * 32];
    __shared__ short Bsl[128 * 32];

    const int tid = threadIdx.x;
    const int z = blockIdx.z;
    const int m0 = blockIdx.y * 128, n0 = blockIdx.x * 128;
    const int w = tid >> 6, ln = tid & 63;
    const int wm = (w & 1) * 64, wn = (w >> 1) * 64;
    const int lr = ln & 15, lq = ln >> 4;
    const int terms = (z == 2) ? 1 : 3;

    const short* Ah  = (z == 0) ? xh : ch;
    const short* Al  = (z == 0) ? xl : cl;
    const short* Bth = (z == 0) ? WqTh : (z == 1 ? WkvTh : WkvTh + (size_t)1024 * 1024);
    const short* Btl = (z == 0) ? WqTl : WkvTl;   // unused for z==2

    f32x4 acc[4][4];
    #pragma unroll
    for (int mt = 0; mt < 4; ++mt)
        #pragma unroll
        for (int nt = 0; nt < 4; ++nt)
            #pragma unroll
            for (int r = 0; r < 4; ++r) acc[mt][nt][r] = 0.0f;

    for (int k0 = 0; k0 < 1024; k0 += 32) {
        __syncthreads();
        // stage: each plane = 128 rows x 4 chunks(16B) = 512 chunks, 2/thread
        #pragma unroll
        for (int it = 0; it < 2; ++it) {
            const int f = it * 256 + tid;
            const int row = f >> 2, c = f & 3;
            const int cg = c ^ ((row >> 1) & 3);   // source-chunk XOR permute
            const size_t ao = (size_t)(m0 + row) * 1024 + k0 + cg * 8;
            const size_t bo = (size_t)(n0 + row) * 1024 + k0 + cg * 8;
            gl_lds16(Ah  + ao, Ash + f * 8);
            gl_lds16(Bth + bo, Bsh + f * 8);
            if (terms == 3) {
                gl_lds16(Al  + ao, Asl + f * 8);
                gl_lds16(Btl + bo, Bsl + f * 8);
            }
        }
        __syncthreads();

        bf16x8 ah[4], bh[4];
        #pragma unroll
        for (int t = 0; t < 4; ++t) {
            const int ar = wm + t * 16 + lr;
            const int br = wn + t * 16 + lr;
            ah[t] = *(const bf16x8*)(Ash + ar * 32 + ((lq ^ ((ar >> 1) & 3)) << 3));
            bh[t] = *(const bf16x8*)(Bsh + br * 32 + ((lq ^ ((br >> 1) & 3)) << 3));
        }
        #pragma unroll
        for (int mt = 0; mt < 4; ++mt)
            #pragma unroll
            for (int nt = 0; nt < 4; ++nt)
                acc[mt][nt] = __builtin_amdgcn_mfma_f32_16x16x32_bf16(
                    ah[mt], bh[nt], acc[mt][nt], 0, 0, 0);

        if (terms == 3) {
            bf16x8 al[4], bl[4];
            #pragma unroll
            for (int t = 0; t < 4; ++t) {
                const int ar = wm + t * 16 + lr;
                const int br = wn + t * 16 + lr;
                al[t] = *(const bf16x8*)(Asl + ar * 32 + ((lq ^ ((ar >> 1) & 3)) << 3));
                bl[t] = *(const bf16x8*)(Bsl + br * 32 + ((lq ^ ((br >> 1) & 3)) << 3));
            }
            #pragma unroll
            for (int mt = 0; mt < 4; ++mt)
                #pragma unroll
                for (int nt = 0; nt < 4; ++nt) {
                    acc[mt][nt] = __builtin_amdgcn_mfma_f32_16x16x32_bf16(
                        ah[mt], bl[nt], acc[mt][nt], 0, 0, 0);
                    acc[mt][nt] = __builtin_amdgcn_mfma_f32_16x16x32_bf16(
                        al[mt], bh[nt], acc[mt][nt], 0, 0, 0);
                }
        }
    }

    // C/D layout: col = lane&15, row = (lane>>4)*4 + reg
    const float scale = (z == 0) ? 0.125f : 1.0f;
    short* Chi = (z == 0) ? qhp : (z == 1 ? khp : vp);
    short* Clo = (z == 0) ? qlp : klp;
    #pragma unroll
    for (int mt = 0; mt < 4; ++mt)
        #pragma unroll
        for (int nt = 0; nt < 4; ++nt)
            #pragma unroll
            for (int r = 0; r < 4; ++r) {
                const int row = m0 + wm + mt * 16 + lq * 4 + r;
                const int col = n0 + wn + nt * 16 + lr;
                const float v = acc[mt][nt][r] * scale;
                const short hh = f2bf(v);
                Chi[(size_t)row * 1024 + col] = hh;
                if (z != 2)
                    Clo[(size_t)row * 1024 + col] = f2bf(v - bf2f(hh));
            }
}

// ---------------------------------------------------------------------------
// Out-proj GEMM (round-8 version): tile 64x64, gl_lds staging, 1024 blocks.
// fp32 + bias out.
// ---------------------------------------------------------------------------
__global__ __launch_bounds__(256)
void gemm_out(const short* __restrict__ A, const short* __restrict__ Bt,
              float* __restrict__ C, int Md, int Nd, int Kd,
              const float* __restrict__ bias)
{
    __shared__ short As[64 * 64];     // 8 KB
    __shared__ short Bs[64 * 64];     // 8 KB
    const int tid = threadIdx.x;
    const int m0 = blockIdx.y * 64, n0 = blockIdx.x * 64;
    const int w = tid >> 6, ln = tid & 63;
    const int wm = (w & 1) * 32, wn = (w >> 1) * 32;
    const int lr = ln & 15, lq = ln >> 4;

    f32x4 acc[2][2];
    #pragma unroll
    for (int mt = 0; mt < 2; ++mt)
        #pragma unroll
        for (int nt = 0; nt < 2; ++nt)
            #pragma unroll
            for (int r = 0; r < 4; ++r) acc[mt][nt][r] = 0.0f;

    for (int k0 = 0; k0 < Kd; k0 += 64) {
        __syncthreads();
        #pragma unroll
        for (int it = 0; it < 2; ++it) {          // 512 chunks per matrix
            const int f = it * 256 + tid;
            const int row = f >> 3, c8 = f & 7;
            gl_lds16(A  + (size_t)(m0 + row) * Kd + k0 + c8 * 8, As + f * 8);
            gl_lds16(Bt + (size_t)(n0 + row) * Kd + k0 + c8 * 8, Bs + f * 8);
        }
        __syncthreads();
        #pragma unroll
        for (int ks = 0; ks < 2; ++ks) {
            bf16x8 af[2], bfr[2];
            #pragma unroll
            for (int t = 0; t < 2; ++t) {
                af[t]  = *(const bf16x8*)(As + (wm + t * 16 + lr) * 64 + ks * 32 + lq * 8);
                bfr[t] = *(const bf16x8*)(Bs + (wn + t * 16 + lr) * 64 + ks * 32 + lq * 8);
            }
            #pragma unroll
            for (int mt = 0; mt < 2; ++mt)
                #pragma unroll
                for (int nt = 0; nt < 2; ++nt)
                    acc[mt][nt] = __builtin_amdgcn_mfma_f32_16x16x32_bf16(
                        af[mt], bfr[nt], acc[mt][nt], 0, 0, 0);
        }
    }
    #pragma unroll
    for (int mt = 0; mt < 2; ++mt)
        #pragma unroll
        for (int nt = 0; nt < 2; ++nt)
            #pragma unroll
            for (int r = 0; r < 4; ++r) {
                const int row = m0 + wm + mt * 16 + lq * 4 + r;
                const int col = n0 + wn + nt * 16 + lr;
                C[(size_t)row * Nd + col] = acc[mt][nt][r] + bias[col];
            }
}

// ---------------------------------------------------------------------------
// MFMA flash attention v7: 4 waves x 32 q-rows/wave (was 8 x 16).
// Halves total K/V LDS-read traffic (B-fragments reused across 2 m-tiles in
// registers); MFMA/VALU totals unchanged; numerics bit-identical to v6.
// Single barrier/K-tile, K/V dbuf + register prefetch, key-permuted P/V
// (b64 Ps writes), XOR-swizzled LDS (0 conflicts), fixed-max softmax,
// masked rows on the reference's fp32 "s-1e6" grid rint(s*16)/16.
// 128 q-rows/block, 256 threads, LDS 64 KB -> 2 blocks/CU.
// ---------------------------------------------------------------------------
__global__ __launch_bounds__(256, 2)
void flash_v7(const short* __restrict__ qh, const short* __restrict__ ql,
              const short* __restrict__ kh, const short* __restrict__ kl,
              const short* __restrict__ vp, const int* __restrict__ mask,
              short* __restrict__ aob)
{
    const int qt = blockIdx.x, h = blockIdx.y, b = blockIdx.z;
    const int tid = threadIdx.x;
    const int w = tid >> 6, ln = tid & 63;
    const int lr = ln & 15, lq = ln >> 4;

    __shared__ short Kh[2 * 4096];   // 16 KB  [buf][key][d] swizzled
    __shared__ short Kl[2 * 4096];   // 16 KB
    __shared__ short Vt[2 * 4096];   // 16 KB  [buf][d][key'] swizzled
    __shared__ short Ps[128 * 64];   // 16 KB  [row][key'] swizzled (wave-local)

    const size_t qrow0 = (size_t)(b * NQ + qt * 128);

    // Q fragments: wave w owns rows w*32 .. w*32+31 as 2 m-tiles
    bf16x8 aqh[2][2], aql[2][2];   // [mt][ks]
    #pragma unroll
    for (int mt = 0; mt < 2; ++mt)
        #pragma unroll
        for (int ks = 0; ks < 2; ++ks) {
            const size_t qoff = (qrow0 + w * 32 + mt * 16 + lr) * INNER
                              + h * 64 + ks * 32 + lq * 8;
            aqh[mt][ks] = *(const bf16x8*)(qh + qoff);
            aql[mt][ks] = *(const bf16x8*)(ql + qoff);
        }
    float keep[2][4];
    #pragma unroll
    for (int mt = 0; mt < 2; ++mt)
        #pragma unroll
        for (int r = 0; r < 4; ++r)
            keep[mt][r] = (float)mask[b * NQ + qt * 128 + w * 32 + mt * 16 + lq * 4 + r];

    // staging maps (256 threads)
    const int srow = tid >> 3, sc8 = tid & 7;            // K: rows 0..31 / 32..63
    const int kdst0 = sw(srow, sc8), kdst1 = sw(32 + srow, sc8);
    const int idx = tid & 31, dg8 = (tid >> 5) * 8;      // V: key-pairs (j, j+16)
    const int vj  = (idx & 15) + ((idx >> 4) << 5);
    const int kp32 = (idx & 15) * 2 + (idx >> 4);
    int4 rkh[2], rkl[2], rva, rvb;

    {   // prologue: load + stage kt=0 into buf 0
        const size_t koff0 = (size_t)(b * NKV + srow) * INNER + h * 64 + sc8 * 8;
        const size_t koff1 = (size_t)(b * NKV + 32 + srow) * INNER + h * 64 + sc8 * 8;
        rkh[0] = *(const int4*)(kh + koff0); rkh[1] = *(const int4*)(kh + koff1);
        rkl[0] = *(const int4*)(kl + koff0); rkl[1] = *(const int4*)(kl + koff1);
        const short* v0 = vp + (size_t)(b * NKV + vj) * INNER + h * 64 + dg8;
        rva = *(const int4*)(v0);
        rvb = *(const int4*)(v0 + 16 * INNER);
        *(int4*)(Kh + kdst0) = rkh[0]; *(int4*)(Kh + kdst1) = rkh[1];
        *(int4*)(Kl + kdst0) = rkl[0]; *(int4*)(Kl + kdst1) = rkl[1];
        const short* as = (const short*)&rva;
        const short* bs = (const short*)&rvb;
        int* vt32 = (int*)Vt;
        #pragma unroll
        for (int j = 0; j < 8; ++j)
            vt32[(dg8 + j) * 32 + (((kp32 >> 2) ^ ((dg8 + j) & 7)) << 2) + (kp32 & 3)] =
                (int)((unsigned short)as[j] | ((unsigned int)(unsigned short)bs[j] << 16));
    }

    float psum[2][4];
    #pragma unroll
    for (int mt = 0; mt < 2; ++mt)
        #pragma unroll
        for (int r = 0; r < 4; ++r) psum[mt][r] = 0.0f;
    f32x4 oacc[2][4];   // [mt][dg]
    #pragma unroll
    for (int mt = 0; mt < 2; ++mt)
        #pragma unroll
        for (int dg = 0; dg < 4; ++dg)
            #pragma unroll
            for (int r = 0; r < 4; ++r) oacc[mt][dg][r] = 0.0f;

    for (int kt = 0; kt < NKV / 64; ++kt) {
        const int cur = kt & 1;
        if (kt < NKV / 64 - 1) {
            const size_t krow0 = (size_t)(b * NKV + (kt + 1) * 64);
            const size_t koff0 = (krow0 + srow) * INNER + h * 64 + sc8 * 8;
            const size_t koff1 = (krow0 + 32 + srow) * INNER + h * 64 + sc8 * 8;
            rkh[0] = *(const int4*)(kh + koff0); rkh[1] = *(const int4*)(kh + koff1);
            rkl[0] = *(const int4*)(kl + koff0); rkl[1] = *(const int4*)(kl + koff1);
            const short* v0 = vp + (krow0 + vj) * INNER + h * 64 + dg8;
            rva = *(const int4*)(v0);
            rvb = *(const int4*)(v0 + 16 * INNER);
        }
        __syncthreads();   // buf[cur] staged; prev iter's reads of buf[cur^1] done

        const short* KhC = Kh + cur * 4096;
        const short* KlC = Kl + cur * 4096;
        const short* VtC = Vt + cur * 4096;

        // S = (Qh+Ql)(Kh+Kl)^T, lo*lo dropped; B-frags shared across m-tiles
        f32x4 sacc[2][4];
        #pragma unroll
        for (int mt = 0; mt < 2; ++mt)
            #pragma unroll
            for (int g = 0; g < 4; ++g)
                #pragma unroll
                for (int r = 0; r < 4; ++r) sacc[mt][g][r] = 0.0f;
        #pragma unroll
        for (int ks = 0; ks < 2; ++ks) {
            #pragma unroll
            for (int g = 0; g < 4; ++g) {
                const bf16x8 bkh = *(const bf16x8*)(KhC + sw(g * 16 + lr, ks * 4 + lq));
                const bf16x8 bkl = *(const bf16x8*)(KlC + sw(g * 16 + lr, ks * 4 + lq));
                #pragma unroll
                for (int mt = 0; mt < 2; ++mt) {
                    sacc[mt][g] = __builtin_amdgcn_mfma_f32_16x16x32_bf16(
                        aqh[mt][ks], bkh, sacc[mt][g], 0, 0, 0);
                    sacc[mt][g] = __builtin_amdgcn_mfma_f32_16x16x32_bf16(
                        aqh[mt][ks], bkl, sacc[mt][g], 0, 0, 0);
                    sacc[mt][g] = __builtin_amdgcn_mfma_f32_16x16x32_bf16(
                        aql[mt][ks], bkh, sacc[mt][g], 0, 0, 0);
                }
            }
        }

        // softmax (fixed max=0) + Ps write: keys' lr*4+g contiguous -> b64
        #pragma unroll
        for (int mt = 0; mt < 2; ++mt)
            #pragma unroll
            for (int r = 0; r < 4; ++r) {
                const int prow = w * 32 + mt * 16 + lq * 4 + r;
                float pv[4];
                #pragma unroll
                for (int g = 0; g < 4; ++g) {
                    float s = sacc[mt][g][r];
                    if (keep[mt][r] == 0.0f) s = rintf(s * 16.0f) * 0.0625f;
                    pv[g] = __expf(s);
                    psum[mt][r] += pv[g];
                }
                short4 pw;
                pw.x = f2bf(pv[0]); pw.y = f2bf(pv[1]);
                pw.z = f2bf(pv[2]); pw.w = f2bf(pv[3]);
                *(short4*)(Ps + sw(prow, lr >> 1) + (lr & 1) * 4) = pw;
            }
        // no barrier: Ps rows are wave-local

        // O += P V; V-frags shared across m-tiles
        #pragma unroll
        for (int ks = 0; ks < 2; ++ks) {
            bf16x8 ap[2];
            #pragma unroll
            for (int mt = 0; mt < 2; ++mt)
                ap[mt] = *(const bf16x8*)(Ps + sw(w * 32 + mt * 16 + lr, ks * 4 + lq));
            #pragma unroll
            for (int dg = 0; dg < 4; ++dg) {
                const bf16x8 bv = *(const bf16x8*)(VtC + sw(dg * 16 + lr, ks * 4 + lq));
                #pragma unroll
                for (int mt = 0; mt < 2; ++mt)
                    oacc[mt][dg] = __builtin_amdgcn_mfma_f32_16x16x32_bf16(
                        ap[mt], bv, oacc[mt][dg], 0, 0, 0);
            }
        }

        if (kt < NKV / 64 - 1) {
            short* KhN = Kh + (cur ^ 1) * 4096;
            short* KlN = Kl + (cur ^ 1) * 4096;
            *(int4*)(KhN + kdst0) = rkh[0]; *(int4*)(KhN + kdst1) = rkh[1];
            *(int4*)(KlN + kdst0) = rkl[0]; *(int4*)(KlN + kdst1) = rkl[1];
            const short* as = (const short*)&rva;
            const short* bs = (const short*)&rvb;
            int* vt32 = (int*)(Vt + (cur ^ 1) * 4096);
            #pragma unroll
            for (int j = 0; j < 8; ++j)
                vt32[(dg8 + j) * 32 + (((kp32 >> 2) ^ ((dg8 + j) & 7)) << 2) + (kp32 & 3)] =
                    (int)((unsigned short)as[j] | ((unsigned int)(unsigned short)bs[j] << 16));
        }
    }

    // final l reduction across the 16 lr-lanes, then normalize + write
    #pragma unroll
    for (int off = 1; off < 16; off <<= 1)
        #pragma unroll
        for (int mt = 0; mt < 2; ++mt)
            #pragma unroll
            for (int r = 0; r < 4; ++r)
                psum[mt][r] += __shfl_xor(psum[mt][r], off, 64);

    #pragma unroll
    for (int mt = 0; mt < 2; ++mt)
        #pragma unroll
        for (int dg = 0; dg < 4; ++dg)
            #pragma unroll
            for (int r = 0; r < 4; ++r) {
                const int row = w * 32 + mt * 16 + lq * 4 + r;
                aob[(qrow0 + row) * INNER + h * 64 + dg * 16 + lr] =
                    f2bf(oacc[mt][dg][r] / psum[mt][r]);
            }
}

// ---------------------------------------------------------------------------
extern "C" void kernel_launch(void* const* d_in, const int* in_sizes, int n_in,
                              void* d_out, int out_size, void* d_ws, size_t ws_size,
                              hipStream_t stream)
{
    const float* x    = (const float*)d_in[0];
    const float* ctx  = (const float*)d_in[1];
    const int*   mask = (const int*)d_in[2];
    const float* Wq   = (const float*)d_in[3];
    const float* Wkv  = (const float*)d_in[4];
    const float* Wout = (const float*)d_in[5];
    const float* bout = (const float*)d_in[6];
    float* out = (float*)d_out;

    // Workspace: 43M shorts = 86 MB (proven). aob aliases xh (dead after qkv).
    short* base  = (short*)d_ws;
    short* xh    = base;                             // 4M ; aob after qkv
    short* xl    = base + (size_t)4 * 1024 * 1024;   // 4M
    short* aob   = xh;
    short* WqTh  = base + (size_t) 8 * 1024 * 1024;  // 1M
    short* WqTl  = base + (size_t) 9 * 1024 * 1024;  // 1M
    short* qhp   = base + (size_t)10 * 1024 * 1024;  // 4M
    short* qlp   = base + (size_t)14 * 1024 * 1024;  // 4M
    short* WkvTh = base + (size_t)18 * 1024 * 1024;  // 2M
    short* WkvTl = base + (size_t)20 * 1024 * 1024;  // 2M
    short* khp   = base + (size_t)22 * 1024 * 1024;  // 4M
    short* klp   = base + (size_t)26 * 1024 * 1024;  // 4M
    short* WoutT = base + (size_t)30 * 1024 * 1024;  // 1M
    short* ch    = base + (size_t)31 * 1024 * 1024;  // 4M
    short* cl    = base + (size_t)35 * 1024 * 1024;  // 4M
    short* vp    = base + (size_t)39 * 1024 * 1024;  // 4M

    const dim3 blk(256);
    // 1) fused prep: split x, split ctx, transpose(+split) weights
    prep_all<<<12288, blk, 0, stream>>>(x, ctx, Wq, Wkv, Wout,
                                        xh, xl, ch, cl,
                                        WqTh, WqTl, WkvTh, WkvTl, WoutT);
    // 2) fused q/k/v GEMM (round-8 version)
    qkv_gemm<<<dim3(8, 32, 3), blk, 0, stream>>>(
        xh, xl, ch, cl, WqTh, WqTl, WkvTh, WkvTl,
        qhp, qlp, khp, klp, vp);
    // 3) attention v7 (aob overwrites xh region, dead after qkv)
    flash_v7<<<dim3(NQ / 128, HEADS, BATCH), blk, 0, stream>>>(
        qhp, qlp, khp, klp, vp, mask, aob);
    // 4) out = ao @ Wout + bout -> fp32
    gemm_out<<<dim3(1024 / 64, 4096 / 64), blk, 0, stream>>>(
        aob, WoutT, out, 4096, 1024, 1024, bout);
}

// Round 12
// 261.909 us; speedup vs baseline: 1.4428x; 1.1421x over previous
//
#include <hip/hip_runtime.h>
#include <hip/hip_bf16.h>
#include <math.h>

// CrossAttention: B=2, N=M=2048, D=1024, H=16, Dh=64
#define BATCH   2
#define NQ      2048
#define NKV     2048
#define DMODEL  1024
#define HEADS   16
#define INNER   1024
#define KVCOLS  2048

typedef short bf16x8 __attribute__((ext_vector_type(8)));
typedef float f32x4  __attribute__((ext_vector_type(4)));

__device__ __forceinline__ short f2bf(float x) {
    __hip_bfloat16 h = __float2bfloat16(x);   // RNE
    return *reinterpret_cast<short*>(&h);
}
__device__ __forceinline__ float bf2f(short h) {
    unsigned int u = ((unsigned int)(unsigned short)h) << 16;
    float f;
    __builtin_memcpy(&f, &u, 4);
    return f;
}
// async 16B global->LDS; per-wave lane-contiguous dest convention (m104)
__device__ __forceinline__ void gl_lds16(const void* g, void* l) {
    __builtin_amdgcn_global_load_lds(
        (const __attribute__((address_space(1))) unsigned int*)g,
        (__attribute__((address_space(3))) unsigned int*)l, 16, 0, 0);
}
// XOR chunk swizzle for stride-64-short LDS rows (chunk = 8 shorts = 16 B)
__device__ __forceinline__ int sw(int row, int chunk) {
    return row * 64 + ((chunk ^ (row & 7)) << 3);
}

// ---------------------------------------------------------------------------
// fused prep: split x, split ctx, transpose(+split) all weights. 12288 blocks.
// ---------------------------------------------------------------------------
__device__ __forceinline__ void split_chunk(const float* __restrict__ in,
                                            short* __restrict__ hi,
                                            short* __restrict__ lo, int id)
{
    const int i = (id * 256 + (int)threadIdx.x) * 4;
    float4 v = *(const float4*)(in + i);
    short4 h, l;
    h.x = f2bf(v.x); l.x = f2bf(v.x - bf2f(h.x));
    h.y = f2bf(v.y); l.y = f2bf(v.y - bf2f(h.y));
    h.z = f2bf(v.z); l.z = f2bf(v.z - bf2f(h.z));
    h.w = f2bf(v.w); l.w = f2bf(v.w - bf2f(h.w));
    *(short4*)(hi + i) = h;
    *(short4*)(lo + i) = l;
}

__device__ __forceinline__ void tile_transpose_split(
    const float* __restrict__ W, short* __restrict__ Wth, short* __restrict__ Wtl,
    int Kd, int Nd, int bx, int by, int split)
{
    __shared__ float t[32][33];
    const int lx = threadIdx.x & 31, ly = threadIdx.x >> 5;
    #pragma unroll
    for (int j = 0; j < 4; ++j)
        t[ly + j * 8][lx] = W[(size_t)(by * 32 + ly + j * 8) * Nd + bx * 32 + lx];
    __syncthreads();
    #pragma unroll
    for (int j = 0; j < 4; ++j) {
        const float v = t[lx][ly + j * 8];
        const short h = f2bf(v);
        const size_t idx = (size_t)(bx * 32 + ly + j * 8) * Kd + by * 32 + lx;
        Wth[idx] = h;
        if (split) Wtl[idx] = f2bf(v - bf2f(h));
    }
}

__global__ __launch_bounds__(256)
void prep_all(const float* __restrict__ x, const float* __restrict__ ctx,
              const float* __restrict__ Wq, const float* __restrict__ Wkv,
              const float* __restrict__ Wout,
              short* __restrict__ xh, short* __restrict__ xl,
              short* __restrict__ ch, short* __restrict__ cl,
              short* __restrict__ WqTh, short* __restrict__ WqTl,
              short* __restrict__ WkvTh, short* __restrict__ WkvTl,
              short* __restrict__ WoutT)
{
    const int id = blockIdx.x;
    if (id < 4096) {
        split_chunk(x, xh, xl, id);
    } else if (id < 8192) {
        split_chunk(ctx, ch, cl, id - 4096);
    } else {
        const int r = id - 8192;
        if (r < 1024)
            tile_transpose_split(Wq, WqTh, WqTl, 1024, 1024, r & 31, r >> 5, 1);
        else if (r < 3072)
            tile_transpose_split(Wkv, WkvTh, WkvTl, 1024, 2048, (r - 1024) & 63, (r - 1024) >> 6, 1);
        else
            tile_transpose_split(Wout, WoutT, nullptr, 1024, 1024, (r - 3072) & 31, (r - 3072) >> 5, 0);
    }
}

// ---------------------------------------------------------------------------
// Fused q/k/v GEMM (round-8 version — fastest measured).
// Tile 128x128, BK=32, 256 threads = 4 waves (wave 64x64), LDS 32 KB, gl_lds
// staging with source-chunk XOR permute (c ^ ((row>>1)&3)) -> free LDS reads.
// Grid (8, 32, 3): z=0 q (3-term, *0.125, split out), z=1 k (3-term, split),
// z=2 v (1-term, bf16). 3-term: C = Ah*Bh + Ah*Bl + Al*Bh.
// ---------------------------------------------------------------------------
__global__ __launch_bounds__(256)
void qkv_gemm(const short* __restrict__ xh, const short* __restrict__ xl,
              const short* __restrict__ ch, const short* __restrict__ cl,
              const short* __restrict__ WqTh, const short* __restrict__ WqTl,
              const short* __restrict__ WkvTh, const short* __restrict__ WkvTl,
              short* __restrict__ qhp, short* __restrict__ qlp,
              short* __restrict__ khp, short* __restrict__ klp,
              short* __restrict__ vp)
{
    __shared__ short Ash[128 * 32];   // 8 KB each
    __shared__ short Asl[128 * 32];
    __shared__ short Bsh[128 * 32];
    __shared__ short Bsl[128 * 32];

    const int tid = threadIdx.x;
    const int z = blockIdx.z;
    const int m0 = blockIdx.y * 128, n0 = blockIdx.x * 128;
    const int w = tid >> 6, ln = tid & 63;
    const int wm = (w & 1) * 64, wn = (w >> 1) * 64;
    const int lr = ln & 15, lq = ln >> 4;
    const int terms = (z == 2) ? 1 : 3;

    const short* Ah  = (z == 0) ? xh : ch;
    const short* Al  = (z == 0) ? xl : cl;
    const short* Bth = (z == 0) ? WqTh : (z == 1 ? WkvTh : WkvTh + (size_t)1024 * 1024);
    const short* Btl = (z == 0) ? WqTl : WkvTl;   // unused for z==2

    f32x4 acc[4][4];
    #pragma unroll
    for (int mt = 0; mt < 4; ++mt)
        #pragma unroll
        for (int nt = 0; nt < 4; ++nt)
            #pragma unroll
            for (int r = 0; r < 4; ++r) acc[mt][nt][r] = 0.0f;

    for (int k0 = 0; k0 < 1024; k0 += 32) {
        __syncthreads();
        // stage: each plane = 128 rows x 4 chunks(16B) = 512 chunks, 2/thread
        #pragma unroll
        for (int it = 0; it < 2; ++it) {
            const int f = it * 256 + tid;
            const int row = f >> 2, c = f & 3;
            const int cg = c ^ ((row >> 1) & 3);   // source-chunk XOR permute
            const size_t ao = (size_t)(m0 + row) * 1024 + k0 + cg * 8;
            const size_t bo = (size_t)(n0 + row) * 1024 + k0 + cg * 8;
            gl_lds16(Ah  + ao, Ash + f * 8);
            gl_lds16(Bth + bo, Bsh + f * 8);
            if (terms == 3) {
                gl_lds16(Al  + ao, Asl + f * 8);
                gl_lds16(Btl + bo, Bsl + f * 8);
            }
        }
        __syncthreads();

        bf16x8 ah[4], bh[4];
        #pragma unroll
        for (int t = 0; t < 4; ++t) {
            const int ar = wm + t * 16 + lr;
            const int br = wn + t * 16 + lr;
            ah[t] = *(const bf16x8*)(Ash + ar * 32 + ((lq ^ ((ar >> 1) & 3)) << 3));
            bh[t] = *(const bf16x8*)(Bsh + br * 32 + ((lq ^ ((br >> 1) & 3)) << 3));
        }
        #pragma unroll
        for (int mt = 0; mt < 4; ++mt)
            #pragma unroll
            for (int nt = 0; nt < 4; ++nt)
                acc[mt][nt] = __builtin_amdgcn_mfma_f32_16x16x32_bf16(
                    ah[mt], bh[nt], acc[mt][nt], 0, 0, 0);

        if (terms == 3) {
            bf16x8 al[4], bl[4];
            #pragma unroll
            for (int t = 0; t < 4; ++t) {
                const int ar = wm + t * 16 + lr;
                const int br = wn + t * 16 + lr;
                al[t] = *(const bf16x8*)(Asl + ar * 32 + ((lq ^ ((ar >> 1) & 3)) << 3));
                bl[t] = *(const bf16x8*)(Bsl + br * 32 + ((lq ^ ((br >> 1) & 3)) << 3));
            }
            #pragma unroll
            for (int mt = 0; mt < 4; ++mt)
                #pragma unroll
                for (int nt = 0; nt < 4; ++nt) {
                    acc[mt][nt] = __builtin_amdgcn_mfma_f32_16x16x32_bf16(
                        ah[mt], bl[nt], acc[mt][nt], 0, 0, 0);
                    acc[mt][nt] = __builtin_amdgcn_mfma_f32_16x16x32_bf16(
                        al[mt], bh[nt], acc[mt][nt], 0, 0, 0);
                }
        }
    }

    // C/D layout: col = lane&15, row = (lane>>4)*4 + reg
    const float scale = (z == 0) ? 0.125f : 1.0f;
    short* Chi = (z == 0) ? qhp : (z == 1 ? khp : vp);
    short* Clo = (z == 0) ? qlp : klp;
    #pragma unroll
    for (int mt = 0; mt < 4; ++mt)
        #pragma unroll
        for (int nt = 0; nt < 4; ++nt)
            #pragma unroll
            for (int r = 0; r < 4; ++r) {
                const int row = m0 + wm + mt * 16 + lq * 4 + r;
                const int col = n0 + wn + nt * 16 + lr;
                const float v = acc[mt][nt][r] * scale;
                const short hh = f2bf(v);
                Chi[(size_t)row * 1024 + col] = hh;
                if (z != 2)
                    Clo[(size_t)row * 1024 + col] = f2bf(v - bf2f(hh));
            }
}

// ---------------------------------------------------------------------------
// Out-proj GEMM v3: tile 128x64, BK=64, gl_lds staging with source-chunk XOR
// permute on BOTH operands (2-way/free LDS reads), LDS 24 KB, grid (16,32).
// fp32 + bias out.
// ---------------------------------------------------------------------------
__global__ __launch_bounds__(256)
void gemm_out(const short* __restrict__ A, const short* __restrict__ Bt,
              float* __restrict__ C, const float* __restrict__ bias)
{
    __shared__ short As[128 * 64];    // 16 KB
    __shared__ short Bs[64 * 64];     //  8 KB
    const int tid = threadIdx.x;
    const int m0 = blockIdx.y * 128, n0 = blockIdx.x * 64;
    const int w = tid >> 6, ln = tid & 63;
    const int wm = (w & 1) * 64, wn = (w >> 1) * 32;
    const int lr = ln & 15, lq = ln >> 4;

    f32x4 acc[4][2];
    #pragma unroll
    for (int mt = 0; mt < 4; ++mt)
        #pragma unroll
        for (int nt = 0; nt < 2; ++nt)
            #pragma unroll
            for (int r = 0; r < 4; ++r) acc[mt][nt][r] = 0.0f;

    for (int k0 = 0; k0 < 1024; k0 += 64) {
        __syncthreads();
        // A: 128 rows x 8 chunks(16B) = 1024 chunks, 4/thread
        #pragma unroll
        for (int it = 0; it < 4; ++it) {
            const int f = it * 256 + tid;
            const int row = f >> 3, c8 = f & 7;
            const int cg = c8 ^ (row & 7);
            gl_lds16(A + (size_t)(m0 + row) * 1024 + k0 + cg * 8, As + f * 8);
        }
        // B: 64 rows x 8 chunks = 512 chunks, 2/thread
        #pragma unroll
        for (int it = 0; it < 2; ++it) {
            const int f = it * 256 + tid;
            const int row = f >> 3, c8 = f & 7;
            const int cg = c8 ^ (row & 7);
            gl_lds16(Bt + (size_t)(n0 + row) * 1024 + k0 + cg * 8, Bs + f * 8);
        }
        __syncthreads();
        #pragma unroll
        for (int ks = 0; ks < 2; ++ks) {
            bf16x8 af[4], bfr[2];
            #pragma unroll
            for (int t = 0; t < 4; ++t) {
                const int ar = wm + t * 16 + lr;
                af[t] = *(const bf16x8*)(As + ar * 64 + (((ks * 4 + lq) ^ (ar & 7)) << 3));
            }
            #pragma unroll
            for (int t = 0; t < 2; ++t) {
                const int br = wn + t * 16 + lr;
                bfr[t] = *(const bf16x8*)(Bs + br * 64 + (((ks * 4 + lq) ^ (br & 7)) << 3));
            }
            #pragma unroll
            for (int mt = 0; mt < 4; ++mt)
                #pragma unroll
                for (int nt = 0; nt < 2; ++nt)
                    acc[mt][nt] = __builtin_amdgcn_mfma_f32_16x16x32_bf16(
                        af[mt], bfr[nt], acc[mt][nt], 0, 0, 0);
        }
    }
    #pragma unroll
    for (int mt = 0; mt < 4; ++mt)
        #pragma unroll
        for (int nt = 0; nt < 2; ++nt)
            #pragma unroll
            for (int r = 0; r < 4; ++r) {
                const int row = m0 + wm + mt * 16 + lq * 4 + r;
                const int col = n0 + wn + nt * 16 + lr;
                C[(size_t)row * 1024 + col] = acc[mt][nt][r] + bias[col];
            }
}

// ---------------------------------------------------------------------------
// MFMA flash attention v6 (round-9 version restored — best measured flash):
// 512 threads = 8 waves x 16 q-rows, single barrier/K-tile, K/V dbuf +
// register prefetch, key-permuted P/V (b64 Ps writes), XOR-swizzled LDS
// (0 conflicts), fixed-max softmax, masked rows on the reference's fp32
// "s-1e6" grid rint(s*16)/16.
// ---------------------------------------------------------------------------
__global__ __launch_bounds__(512, 4)
void flash_v6(const short* __restrict__ qh, const short* __restrict__ ql,
              const short* __restrict__ kh, const short* __restrict__ kl,
              const short* __restrict__ vp, const int* __restrict__ mask,
              short* __restrict__ aob)
{
    const int qt = blockIdx.x, h = blockIdx.y, b = blockIdx.z;
    const int tid = threadIdx.x;
    const int w = tid >> 6, ln = tid & 63;
    const int lr = ln & 15, lq = ln >> 4;

    __shared__ short Kh[2 * 4096];   // 16 KB  [buf][key][d] swizzled
    __shared__ short Kl[2 * 4096];   // 16 KB
    __shared__ short Vt[2 * 4096];   // 16 KB  [buf][d][key'] swizzled
    __shared__ short Ps[128 * 64];   // 16 KB  [row][key'] swizzled (wave-local)

    const size_t qrow0 = (size_t)(b * NQ + qt * 128);

    bf16x8 aqh[2], aql[2];
    #pragma unroll
    for (int ks = 0; ks < 2; ++ks) {
        const size_t qoff = (qrow0 + w * 16 + lr) * INNER + h * 64 + ks * 32 + lq * 8;
        aqh[ks] = *(const bf16x8*)(qh + qoff);
        aql[ks] = *(const bf16x8*)(ql + qoff);
    }
    float keep[4];
    #pragma unroll
    for (int r = 0; r < 4; ++r)
        keep[r] = (float)mask[b * NQ + qt * 128 + w * 16 + lq * 4 + r];

    const int srow = tid >> 3, sc8 = tid & 7;            // K: 64 rows x 8 chunks
    const int kdst = sw(srow, sc8);
    const int idx = tid & 31, dg4 = (tid >> 5) * 4;      // V: key-pairs (j, j+16)
    const int vj  = (idx & 15) + ((idx >> 4) << 5);
    const int kp32 = (idx & 15) * 2 + (idx >> 4);
    int4 rkh, rkl; int2 rva, rvb;

    {   // prologue: load + stage kt=0 into buf 0
        const size_t koff = (size_t)(b * NKV + srow) * INNER + h * 64 + sc8 * 8;
        rkh = *(const int4*)(kh + koff);
        rkl = *(const int4*)(kl + koff);
        const short* v0 = vp + (size_t)(b * NKV + vj) * INNER + h * 64 + dg4;
        rva = *(const int2*)(v0);
        rvb = *(const int2*)(v0 + 16 * INNER);
        *(int4*)(Kh + kdst) = rkh;
        *(int4*)(Kl + kdst) = rkl;
        const short* as = (const short*)&rva;
        const short* bs = (const short*)&rvb;
        int* vt32 = (int*)Vt;
        #pragma unroll
        for (int j = 0; j < 4; ++j)
            vt32[(dg4 + j) * 32 + (((kp32 >> 2) ^ ((dg4 + j) & 7)) << 2) + (kp32 & 3)] =
                (int)((unsigned short)as[j] | ((unsigned int)(unsigned short)bs[j] << 16));
    }

    float psum[4];
    #pragma unroll
    for (int r = 0; r < 4; ++r) psum[r] = 0.0f;
    f32x4 oacc[4];
    #pragma unroll
    for (int dg = 0; dg < 4; ++dg)
        #pragma unroll
        for (int r = 0; r < 4; ++r) oacc[dg][r] = 0.0f;

    for (int kt = 0; kt < NKV / 64; ++kt) {
        const int cur = kt & 1;
        if (kt < NKV / 64 - 1) {
            const size_t krow0 = (size_t)(b * NKV + (kt + 1) * 64);
            const size_t koff = (krow0 + srow) * INNER + h * 64 + sc8 * 8;
            rkh = *(const int4*)(kh + koff);
            rkl = *(const int4*)(kl + koff);
            const short* v0 = vp + (krow0 + vj) * INNER + h * 64 + dg4;
            rva = *(const int2*)(v0);
            rvb = *(const int2*)(v0 + 16 * INNER);
        }
        __syncthreads();

        const short* KhC = Kh + cur * 4096;
        const short* KlC = Kl + cur * 4096;
        const short* VtC = Vt + cur * 4096;

        f32x4 sacc[4];
        #pragma unroll
        for (int g = 0; g < 4; ++g)
            #pragma unroll
            for (int r = 0; r < 4; ++r) sacc[g][r] = 0.0f;
        #pragma unroll
        for (int ks = 0; ks < 2; ++ks) {
            #pragma unroll
            for (int g = 0; g < 4; ++g) {
                const bf16x8 bkh = *(const bf16x8*)(KhC + sw(g * 16 + lr, ks * 4 + lq));
                const bf16x8 bkl = *(const bf16x8*)(KlC + sw(g * 16 + lr, ks * 4 + lq));
                sacc[g] = __builtin_amdgcn_mfma_f32_16x16x32_bf16(aqh[ks], bkh, sacc[g], 0, 0, 0);
                sacc[g] = __builtin_amdgcn_mfma_f32_16x16x32_bf16(aqh[ks], bkl, sacc[g], 0, 0, 0);
                sacc[g] = __builtin_amdgcn_mfma_f32_16x16x32_bf16(aql[ks], bkh, sacc[g], 0, 0, 0);
            }
        }

        // softmax (fixed max=0) + Ps write: keys' lr*4+g contiguous -> b64
        #pragma unroll
        for (int r = 0; r < 4; ++r) {
            const int prow = w * 16 + lq * 4 + r;
            float pv[4];
            #pragma unroll
            for (int g = 0; g < 4; ++g) {
                float s = sacc[g][r];
                if (keep[r] == 0.0f) s = rintf(s * 16.0f) * 0.0625f;
                pv[g] = __expf(s);
                psum[r] += pv[g];
            }
            short4 pw;
            pw.x = f2bf(pv[0]); pw.y = f2bf(pv[1]);
            pw.z = f2bf(pv[2]); pw.w = f2bf(pv[3]);
            *(short4*)(Ps + sw(prow, lr >> 1) + (lr & 1) * 4) = pw;
        }
        // no barrier: Ps rows are wave-local

        #pragma unroll
        for (int ks = 0; ks < 2; ++ks) {
            const bf16x8 ap = *(const bf16x8*)(Ps + sw(w * 16 + lr, ks * 4 + lq));
            #pragma unroll
            for (int dg = 0; dg < 4; ++dg) {
                const bf16x8 bv = *(const bf16x8*)(VtC + sw(dg * 16 + lr, ks * 4 + lq));
                oacc[dg] = __builtin_amdgcn_mfma_f32_16x16x32_bf16(ap, bv, oacc[dg], 0, 0, 0);
            }
        }

        if (kt < NKV / 64 - 1) {
            short* KhN = Kh + (cur ^ 1) * 4096;
            short* KlN = Kl + (cur ^ 1) * 4096;
            *(int4*)(KhN + kdst) = rkh;
            *(int4*)(KlN + kdst) = rkl;
            const short* as = (const short*)&rva;
            const short* bs = (const short*)&rvb;
            int* vt32 = (int*)(Vt + (cur ^ 1) * 4096);
            #pragma unroll
            for (int j = 0; j < 4; ++j)
                vt32[(dg4 + j) * 32 + (((kp32 >> 2) ^ ((dg4 + j) & 7)) << 2) + (kp32 & 3)] =
                    (int)((unsigned short)as[j] | ((unsigned int)(unsigned short)bs[j] << 16));
        }
    }

    #pragma unroll
    for (int off = 1; off < 16; off <<= 1)
        #pragma unroll
        for (int r = 0; r < 4; ++r)
            psum[r] += __shfl_xor(psum[r], off, 64);

    #pragma unroll
    for (int dg = 0; dg < 4; ++dg)
        #pragma unroll
        for (int r = 0; r < 4; ++r) {
            const int row = w * 16 + lq * 4 + r;
            aob[(qrow0 + row) * INNER + h * 64 + dg * 16 + lr] =
                f2bf(oacc[dg][r] / psum[r]);
        }
}

// ---------------------------------------------------------------------------
extern "C" void kernel_launch(void* const* d_in, const int* in_sizes, int n_in,
                              void* d_out, int out_size, void* d_ws, size_t ws_size,
                              hipStream_t stream)
{
    const float* x    = (const float*)d_in[0];
    const float* ctx  = (const float*)d_in[1];
    const int*   mask = (const int*)d_in[2];
    const float* Wq   = (const float*)d_in[3];
    const float* Wkv  = (const float*)d_in[4];
    const float* Wout = (const float*)d_in[5];
    const float* bout = (const float*)d_in[6];
    float* out = (float*)d_out;

    // Workspace: 43M shorts = 86 MB (proven). aob aliases xh (dead after qkv).
    short* base  = (short*)d_ws;
    short* xh    = base;                             // 4M ; aob after qkv
    short* xl    = base + (size_t)4 * 1024 * 1024;   // 4M
    short* aob   = xh;
    short* WqTh  = base + (size_t) 8 * 1024 * 1024;  // 1M
    short* WqTl  = base + (size_t) 9 * 1024 * 1024;  // 1M
    short* qhp   = base + (size_t)10 * 1024 * 1024;  // 4M
    short* qlp   = base + (size_t)14 * 1024 * 1024;  // 4M
    short* WkvTh = base + (size_t)18 * 1024 * 1024;  // 2M
    short* WkvTl = base + (size_t)20 * 1024 * 1024;  // 2M
    short* khp   = base + (size_t)22 * 1024 * 1024;  // 4M
    short* klp   = base + (size_t)26 * 1024 * 1024;  // 4M
    short* WoutT = base + (size_t)30 * 1024 * 1024;  // 1M
    short* ch    = base + (size_t)31 * 1024 * 1024;  // 4M
    short* cl    = base + (size_t)35 * 1024 * 1024;  // 4M
    short* vp    = base + (size_t)39 * 1024 * 1024;  // 4M

    const dim3 blk(256);
    // 1) fused prep: split x, split ctx, transpose(+split) weights
    prep_all<<<12288, blk, 0, stream>>>(x, ctx, Wq, Wkv, Wout,
                                        xh, xl, ch, cl,
                                        WqTh, WqTl, WkvTh, WkvTl, WoutT);
    // 2) fused q/k/v GEMM (round-8 version)
    qkv_gemm<<<dim3(8, 32, 3), blk, 0, stream>>>(
        xh, xl, ch, cl, WqTh, WqTl, WkvTh, WkvTl,
        qhp, qlp, khp, klp, vp);
    // 3) attention v6 (aob overwrites xh region, dead after qkv)
    flash_v6<<<dim3(NQ / 128, HEADS, BATCH), dim3(512), 0, stream>>>(
        qhp, qlp, khp, klp, vp, mask, aob);
    // 4) out = ao @ Wout + bout -> fp32
    gemm_out<<<dim3(1024 / 64, 4096 / 128), blk, 0, stream>>>(
        aob, WoutT, out, bout);
}